// Round 3
// baseline (405.200 us; speedup 1.0000x reference)
//
#include <hip/hip_runtime.h>
#include <hip/hip_bf16.h>

typedef __bf16 bf16x8 __attribute__((ext_vector_type(8)));
typedef __bf16 bf16x4 __attribute__((ext_vector_type(4)));
typedef float  f32x4  __attribute__((ext_vector_type(4)));

#define BT    2048
#define MDIM  48

// ws byte offsets
#define WS_WVID  0                       // K-major granule layout, 512 KB
#define WS_WV    (512*512*2)
#define WS_WG    (WS_WV + 48*512*2)
#define WS_INTER (WS_WG + 48*512*2)

// ---------------------------------------------------------------- kernel 0
// W_video [512h x 512k] row-major fp32 -> K-major granule bf16:
// granule (kc,h), kc=0..63, at flat16 = kc*512 + h, holds W_video[h][kc*8..kc*8+7].
// W_v / W_g stay row-major bf16.
__global__ __launch_bounds__(256) void convert_weights(
    const float* __restrict__ Wvid, const float* __restrict__ Wv,
    const float* __restrict__ Wg,
    __bf16* __restrict__ wvid_k, __bf16* __restrict__ wv_b,
    __bf16* __restrict__ wg_b) {
    int i = blockIdx.x * blockDim.x + threadIdx.x;
    const int nv = 65536, n2 = 6144;
    if (i < nv) {
        int h = i >> 7, k4 = i & 127;    // 128 float4 per 512-elem row
        float4 f = ((const float4*)Wvid)[i];
        bf16x4 o = {(__bf16)f.x, (__bf16)f.y, (__bf16)f.z, (__bf16)f.w};
        *(bf16x4*)(wvid_k + (size_t)(((k4 >> 1) * 512 + h) * 8 + (k4 & 1) * 4)) = o;
    } else if (i < nv + n2) {
        int j = i - nv;
        float4 f = ((const float4*)Wv)[j];
        bf16x4 o = {(__bf16)f.x, (__bf16)f.y, (__bf16)f.z, (__bf16)f.w};
        ((bf16x4*)wv_b)[j] = o;
    } else {
        int j = i - nv - n2;
        float4 f = ((const float4*)Wg)[j];
        bf16x4 o = {(__bf16)f.x, (__bf16)f.y, (__bf16)f.z, (__bf16)f.w};
        ((bf16x4*)wg_b)[j] = o;
    }
}

// ---------------------------------------------------------------- kernel 1
__global__ __launch_bounds__(512) void audio_batch(
    const float* __restrict__ audio, const float* __restrict__ Wa,
    const float* __restrict__ ba, const __bf16* __restrict__ wg_b,
    float* __restrict__ inter) {
    __shared__ float  ain[16 * 128];
    __shared__ __bf16 as_s[64 * 17 * 8];

    const int bt0 = blockIdx.x * 16;
    const int t   = threadIdx.x;

    ((float4*)ain)[t] = ((const float4*)(audio + (size_t)bt0 * 128))[t];
    __syncthreads();

    float acc[16];
    float bias = ba[t];
    #pragma unroll
    for (int b = 0; b < 16; ++b) acc[b] = bias;
    const float4* wr = (const float4*)(Wa + (size_t)t * 128);
    #pragma unroll 4
    for (int k4 = 0; k4 < 32; ++k4) {
        float4 wv = wr[k4];
        #pragma unroll
        for (int b = 0; b < 16; ++b) {
            float4 av = ((const float4*)ain)[b * 32 + k4];
            acc[b] += av.x*wv.x + av.y*wv.y + av.z*wv.z + av.w*wv.w;
        }
    }
    #pragma unroll
    for (int b = 0; b < 16; ++b)
        as_s[(((t >> 3) * 17 + b) << 3) | (t & 7)] = (__bf16)fmaxf(acc[b], 0.f);
    __syncthreads();

    const int w = t >> 6, lane = t & 63, l16 = lane & 15, quad = lane >> 4;
    if (w < 3) {
        f32x4 c = {0.f, 0.f, 0.f, 0.f};
        const __bf16* bp = wg_b + (size_t)(w * 16 + l16) * 512 + quad * 8;
        const __bf16* ap = &as_s[((quad * 17 + l16)) * 8];
        bf16x8 aC = *(const bf16x8*)ap;
        bf16x8 bC = *(const bf16x8*)bp;
        #pragma unroll
        for (int kt = 0; kt < 16; ++kt) {
            bf16x8 aN, bN;
            if (kt < 15) {
                aN = *(const bf16x8*)(ap + (kt + 1) * (4 * 17 * 8));
                bN = *(const bf16x8*)(bp + (kt + 1) * 32);
            }
            c = __builtin_amdgcn_mfma_f32_16x16x32_bf16(aC, bC, c, 0, 0, 0);
            if (kt < 15) { aC = aN; bC = bN; }
        }
        #pragma unroll
        for (int r = 0; r < 4; ++r)
            inter[(size_t)(bt0 + quad * 4 + r) * 48 + w * 16 + l16] = c[r];
    }
}

// ---------------------------------------------------------------- kernel 2
// Deep-pipelined phase-1/2: 4 chunks x 4 kt. V staged by waves 0-5 (tid<384),
// 2 granules/thread/chunk (16 kc x 48 s = 768 granules). Loads for chunk c+2
// are issued at the END of iteration c (after the c+1 ds_write), giving an
// issue->ds_write distance of one full chunk (~48 MFMA/wave + barrier), which
// covers HBM latency. Only ONE load set in flight (+16 VGPR).
// launch_bounds(512,4): VGPR cap 128. (512,6) clamped VGPR to 40 -> 400 MB
// scratch spill, 275 us. Keep VGPR <= 84 so 3 blocks/CU (LDS-bound) stay
// schedulable (512/6 waves per SIMD = 85 VGPR ceiling).
__global__ __launch_bounds__(512, 4) void main_fused(
    const float* __restrict__ video, const float* __restrict__ bvid,
    const __bf16* __restrict__ wvid_k, const __bf16* __restrict__ wv_b,
    const float* __restrict__ Wh, const float* __restrict__ inter_g,
    float* __restrict__ out) {

    __shared__ uint4 pool4[3136];        // 50176 B: V granules, later vact rows
    __shared__ float inter_s[MDIM];
    __shared__ float z_s[MDIM];
    __shared__ float alpha_s[MDIM];
    __shared__ float content8[256];

    char* pool = (char*)pool4;

    const int bt   = blockIdx.x;
    const int tid  = threadIdx.x;
    const int w    = tid >> 6;
    const int lane = tid & 63;
    const int l16  = lane & 15;
    const int quad = lane >> 4;

    const float* Vg = video + (size_t)bt * (48 * 512);
    const char*  bbase = (const char*)wvid_k;

    // ---- phase 0
    if (tid < MDIM) { inter_s[tid] = inter_g[bt * MDIM + tid]; z_s[tid] = 0.f; }
    if (tid < 256) content8[tid] = 0.f;

    // staging ids: waves 0-5 (tid<384), 2 granules per chunk:
    // (s_a0, kc) and (s_a1, kc) with kc = c*16 + kcl.
    // 16 lanes per s-row -> 512B contiguous global reads per row.
    const int  s_a0   = tid >> 4;        // 0..23
    const int  s_a1   = s_a0 + 24;       // 24..47
    const int  kcl    = tid & 15;        // 0..15
    const bool stager = (tid < 384);

    // ---- prologue: stage chunk 0 (kc 0..15), issue loads for chunk 1
    float4 rx0, ry0, rx1, ry1;           // in-flight loads for chunk c+1
    if (stager) {
        const float4* p = (const float4*)(Vg + s_a0 * 512 + kcl * 8);
        const float4* q = (const float4*)(Vg + s_a1 * 512 + kcl * 8);
        float4 x0 = p[0], y0 = p[1], x1 = q[0], y1 = q[1];
        bf16x8 g0 = {(__bf16)x0.x, (__bf16)x0.y, (__bf16)x0.z, (__bf16)x0.w,
                     (__bf16)y0.x, (__bf16)y0.y, (__bf16)y0.z, (__bf16)y0.w};
        bf16x8 g1 = {(__bf16)x1.x, (__bf16)x1.y, (__bf16)x1.z, (__bf16)x1.w,
                     (__bf16)y1.x, (__bf16)y1.y, (__bf16)y1.z, (__bf16)y1.w};
        *(bf16x8*)(pool + (kcl * 49 + s_a0) * 16) = g0;
        *(bf16x8*)(pool + (kcl * 49 + s_a1) * 16) = g1;
        // issue chunk-1 loads now; ds_write happens after chunk-0 compute
        const float4* p1 = (const float4*)(Vg + s_a0 * 512 + (16 + kcl) * 8);
        const float4* q1 = (const float4*)(Vg + s_a1 * 512 + (16 + kcl) * 8);
        rx0 = p1[0]; ry0 = p1[1]; rx1 = q1[0]; ry1 = q1[1];
    }

    // first B fragments (kt = 0) issued before the barrier
    const int bIdx0 = quad * 8192 + (w * 64 + l16) * 16;
    bf16x8 bC[4];
    #pragma unroll
    for (int j = 0; j < 4; ++j)
        bC[j] = *(const bf16x8*)(bbase + bIdx0 + j * 256);

    f32x4 acc[3][4];
    #pragma unroll
    for (int mt = 0; mt < 3; ++mt)
        #pragma unroll
        for (int j = 0; j < 4; ++j) {
            f32x4 z = {0.f, 0.f, 0.f, 0.f};
            acc[mt][j] = z;
        }

    __syncthreads();

    // ---- pipelined phase 1+2: 4 chunks x 4 kt
    #pragma unroll
    for (int c = 0; c < 4; ++c) {
        #pragma unroll
        for (int k = 0; k < 4; ++k) {
            const int kt = c * 4 + k;
            bf16x8 bN[4];
            if (kt < 15) {
                #pragma unroll
                for (int j = 0; j < 4; ++j)
                    bN[j] = *(const bf16x8*)(bbase + bIdx0 + (kt + 1) * 32768 + j * 256);
            }
            bf16x8 a[3];
            #pragma unroll
            for (int mt = 0; mt < 3; ++mt)
                a[mt] = *(const bf16x8*)(pool + ((4 * kt + quad) * 49 + mt * 16 + l16) * 16);
            #pragma unroll
            for (int mt = 0; mt < 3; ++mt)
                #pragma unroll
                for (int j = 0; j < 4; ++j)
                    acc[mt][j] = __builtin_amdgcn_mfma_f32_16x16x32_bf16(
                                     a[mt], bC[j], acc[mt][j], 0, 0, 0);
            if (kt < 15) {
                #pragma unroll
                for (int j = 0; j < 4; ++j) bC[j] = bN[j];
            }
        }
        if (c < 3 && stager) {
            // ds_write chunk c+1 (loads issued one full chunk ago)
            const int kc = (c + 1) * 16 + kcl;
            bf16x8 g0 = {(__bf16)rx0.x, (__bf16)rx0.y, (__bf16)rx0.z, (__bf16)rx0.w,
                         (__bf16)ry0.x, (__bf16)ry0.y, (__bf16)ry0.z, (__bf16)ry0.w};
            bf16x8 g1 = {(__bf16)rx1.x, (__bf16)rx1.y, (__bf16)rx1.z, (__bf16)rx1.w,
                         (__bf16)ry1.x, (__bf16)ry1.y, (__bf16)ry1.z, (__bf16)ry1.w};
            *(bf16x8*)(pool + (kc * 49 + s_a0) * 16) = g0;
            *(bf16x8*)(pool + (kc * 49 + s_a1) * 16) = g1;
            if (c < 2) {
                // issue loads for chunk c+2 (single set in flight)
                const int kc2 = (c + 2) * 16 + kcl;
                const float4* p = (const float4*)(Vg + s_a0 * 512 + kc2 * 8);
                const float4* q = (const float4*)(Vg + s_a1 * 512 + kc2 * 8);
                rx0 = p[0]; ry0 = p[1]; rx1 = q[0]; ry1 = q[1];
            }
        }
        __syncthreads();   // chunk c+1 visible; final one fences pool reuse
    }

    // epilogue: relu+bias -> vact rows of 1040 B. D: row(s)=quad*4+r, col(h)=l16
    #pragma unroll
    for (int j = 0; j < 4; ++j) {
        int h = w * 64 + j * 16 + l16;
        float bias = bvid[h];            // L2-hot scalar load
        #pragma unroll
        for (int mt = 0; mt < 3; ++mt) {
            #pragma unroll
            for (int r = 0; r < 4; ++r) {
                int s = mt * 16 + quad * 4 + r;
                *(__bf16*)(pool + s * 1040 + h * 2) =
                    (__bf16)fmaxf(acc[mt][j][r] + bias, 0.f);
            }
        }
    }
    __syncthreads();

    // ---- phase 3: content = vact @ Wv^T + inter; z[s] += tanh(.)*Wh[m]
    {
        int ti = w / 3, tj = w - ti * 3;    // tiles 0..7; tile 8 split below
        const __bf16* bp = wv_b + (size_t)(tj * 16 + l16) * 512 + quad * 8;
        const char*   ap = pool + (ti * 16 + l16) * 1040 + quad * 16;
        // two interleaved accumulators halve the dependent-MFMA chain
        f32x4 c3e = {0.f, 0.f, 0.f, 0.f};
        f32x4 c3o = {0.f, 0.f, 0.f, 0.f};
        #pragma unroll
        for (int kt = 0; kt < 16; kt += 2) {
            bf16x8 a0 = *(const bf16x8*)(ap + kt * 64);
            bf16x8 b0 = *(const bf16x8*)(bp + kt * 32);
            c3e = __builtin_amdgcn_mfma_f32_16x16x32_bf16(a0, b0, c3e, 0, 0, 0);
            bf16x8 a1 = *(const bf16x8*)(ap + (kt + 1) * 64);
            bf16x8 b1 = *(const bf16x8*)(bp + (kt + 1) * 32);
            c3o = __builtin_amdgcn_mfma_f32_16x16x32_bf16(a1, b1, c3o, 0, 0, 0);
        }
        f32x4 c3 = c3e + c3o;
        float wh = Wh[tj * 16 + l16];
        #pragma unroll
        for (int r = 0; r < 4; ++r) {
            int s = ti * 16 + quad * 4 + r;
            float contrib = tanhf(c3[r] + inter_s[s]) * wh;
            contrib += __shfl_xor(contrib, 1);
            contrib += __shfl_xor(contrib, 2);
            contrib += __shfl_xor(contrib, 4);
            contrib += __shfl_xor(contrib, 8);
            if (l16 == 0) atomicAdd(&z_s[s], contrib);
        }
        // tile 8 (ti=2,tj=2): wave w does kt = 2w, 2w+1
        f32x4 p8 = {0.f, 0.f, 0.f, 0.f};
        #pragma unroll
        for (int q = 0; q < 2; ++q) {
            int kt = 2 * w + q;
            bf16x8 a8 = *(const bf16x8*)(pool + (32 + l16) * 1040 + kt * 64 + quad * 16);
            bf16x8 b8 = *(const bf16x8*)(wv_b + (size_t)(32 + l16) * 512 + kt * 32 + quad * 8);
            p8 = __builtin_amdgcn_mfma_f32_16x16x32_bf16(a8, b8, p8, 0, 0, 0);
        }
        #pragma unroll
        for (int r = 0; r < 4; ++r)
            atomicAdd(&content8[(quad * 4 + r) * 16 + l16], p8[r]);
    }
    __syncthreads();

    if (w == 0) {
        float wh = Wh[32 + l16];
        #pragma unroll
        for (int r = 0; r < 4; ++r) {
            int s = 32 + quad * 4 + r;
            float contrib = tanhf(content8[(quad * 4 + r) * 16 + l16] + inter_s[s]) * wh;
            contrib += __shfl_xor(contrib, 1);
            contrib += __shfl_xor(contrib, 2);
            contrib += __shfl_xor(contrib, 4);
            contrib += __shfl_xor(contrib, 8);
            if (l16 == 0) atomicAdd(&z_s[s], contrib);
        }
    }
    __syncthreads();

    // ---- phase 4: softmax over z[48] (wave 0)
    if (w == 0) {
        float x = (lane < MDIM) ? z_s[lane] : -INFINITY;
        float mx = x;
        #pragma unroll
        for (int off = 32; off >= 1; off >>= 1) mx = fmaxf(mx, __shfl_xor(mx, off));
        float e = (lane < MDIM) ? expf(x - mx) : 0.f;
        float sm = e;
        #pragma unroll
        for (int off = 32; off >= 1; off >>= 1) sm += __shfl_xor(sm, off);
        if (lane < MDIM) alpha_s[lane] = e / sm;
    }
    __syncthreads();

    // ---- phase 5: c[h] = sum_s alpha[s] * V[s][h] (fp32 global, L2/L3-hot)
    float acc5 = 0.f;
    #pragma unroll
    for (int s = 0; s < MDIM; ++s)
        acc5 += alpha_s[s] * Vg[s * 512 + tid];
    out[(size_t)bt * 512 + tid] = acc5;
}

// ---------------------------------------------------------------- launch
extern "C" void kernel_launch(void* const* d_in, const int* in_sizes, int n_in,
                              void* d_out, int out_size, void* d_ws, size_t ws_size,
                              hipStream_t stream) {
    const float* audio   = (const float*)d_in[0];
    const float* video   = (const float*)d_in[1];
    const float* W_audio = (const float*)d_in[2];
    const float* b_audio = (const float*)d_in[3];
    const float* W_video = (const float*)d_in[4];
    const float* b_video = (const float*)d_in[5];
    const float* W_v     = (const float*)d_in[6];
    const float* W_g     = (const float*)d_in[7];
    const float* W_h     = (const float*)d_in[8];
    float* out = (float*)d_out;

    char* ws = (char*)d_ws;
    __bf16* wvid_k = (__bf16*)(ws + WS_WVID);
    __bf16* wv_b   = (__bf16*)(ws + WS_WV);
    __bf16* wg_b   = (__bf16*)(ws + WS_WG);
    float*  inter  = (float*)(ws + WS_INTER);

    convert_weights<<<304, 256, 0, stream>>>(W_video, W_v, W_g, wvid_k, wv_b, wg_b);
    audio_batch<<<BT / 16, 512, 0, stream>>>(audio, W_audio, b_audio, wg_b, inter);
    main_fused<<<BT, 512, 0, stream>>>(video, b_video, wvid_k, wv_b, W_h, inter, out);
}

// Round 4
// 391.759 us; speedup vs baseline: 1.0343x; 1.0343x over previous
//
#include <hip/hip_runtime.h>
#include <hip/hip_bf16.h>

typedef __bf16 bf16x8 __attribute__((ext_vector_type(8)));
typedef __bf16 bf16x4 __attribute__((ext_vector_type(4)));
typedef float  f32x4  __attribute__((ext_vector_type(4)));

#define BT    2048
#define MDIM  48

// ws byte offsets
#define WS_WVID  0                       // K-major granule layout, 512 KB
#define WS_WV    (512*512*2)
#define WS_WG    (WS_WV + 48*512*2)
#define WS_INTER (WS_WG + 48*512*2)

// ---------------------------------------------------------------- kernel 0
// W_video [512h x 512k] row-major fp32 -> K-major granule bf16:
// granule (kc,h), kc=0..63, at flat16 = kc*512 + h, holds W_video[h][kc*8..kc*8+7].
// W_v / W_g stay row-major bf16.
__global__ __launch_bounds__(256) void convert_weights(
    const float* __restrict__ Wvid, const float* __restrict__ Wv,
    const float* __restrict__ Wg,
    __bf16* __restrict__ wvid_k, __bf16* __restrict__ wv_b,
    __bf16* __restrict__ wg_b) {
    int i = blockIdx.x * blockDim.x + threadIdx.x;
    const int nv = 65536, n2 = 6144;
    if (i < nv) {
        int h = i >> 7, k4 = i & 127;    // 128 float4 per 512-elem row
        float4 f = ((const float4*)Wvid)[i];
        bf16x4 o = {(__bf16)f.x, (__bf16)f.y, (__bf16)f.z, (__bf16)f.w};
        *(bf16x4*)(wvid_k + (size_t)(((k4 >> 1) * 512 + h) * 8 + (k4 & 1) * 4)) = o;
    } else if (i < nv + n2) {
        int j = i - nv;
        float4 f = ((const float4*)Wv)[j];
        bf16x4 o = {(__bf16)f.x, (__bf16)f.y, (__bf16)f.z, (__bf16)f.w};
        ((bf16x4*)wv_b)[j] = o;
    } else {
        int j = i - nv - n2;
        float4 f = ((const float4*)Wg)[j];
        bf16x4 o = {(__bf16)f.x, (__bf16)f.y, (__bf16)f.z, (__bf16)f.w};
        ((bf16x4*)wg_b)[j] = o;
    }
}

// ---------------------------------------------------------------- kernel 1
__global__ __launch_bounds__(512) void audio_batch(
    const float* __restrict__ audio, const float* __restrict__ Wa,
    const float* __restrict__ ba, const __bf16* __restrict__ wg_b,
    float* __restrict__ inter) {
    __shared__ float  ain[16 * 128];
    __shared__ __bf16 as_s[64 * 17 * 8];

    const int bt0 = blockIdx.x * 16;
    const int t   = threadIdx.x;

    ((float4*)ain)[t] = ((const float4*)(audio + (size_t)bt0 * 128))[t];
    __syncthreads();

    float acc[16];
    float bias = ba[t];
    #pragma unroll
    for (int b = 0; b < 16; ++b) acc[b] = bias;
    const float4* wr = (const float4*)(Wa + (size_t)t * 128);
    #pragma unroll 4
    for (int k4 = 0; k4 < 32; ++k4) {
        float4 wv = wr[k4];
        #pragma unroll
        for (int b = 0; b < 16; ++b) {
            float4 av = ((const float4*)ain)[b * 32 + k4];
            acc[b] += av.x*wv.x + av.y*wv.y + av.z*wv.z + av.w*wv.w;
        }
    }
    #pragma unroll
    for (int b = 0; b < 16; ++b)
        as_s[(((t >> 3) * 17 + b) << 3) | (t & 7)] = (__bf16)fmaxf(acc[b], 0.f);
    __syncthreads();

    const int w = t >> 6, lane = t & 63, l16 = lane & 15, quad = lane >> 4;
    if (w < 3) {
        f32x4 c = {0.f, 0.f, 0.f, 0.f};
        const __bf16* bp = wg_b + (size_t)(w * 16 + l16) * 512 + quad * 8;
        const __bf16* ap = &as_s[((quad * 17 + l16)) * 8];
        bf16x8 aC = *(const bf16x8*)ap;
        bf16x8 bC = *(const bf16x8*)bp;
        #pragma unroll
        for (int kt = 0; kt < 16; ++kt) {
            bf16x8 aN, bN;
            if (kt < 15) {
                aN = *(const bf16x8*)(ap + (kt + 1) * (4 * 17 * 8));
                bN = *(const bf16x8*)(bp + (kt + 1) * 32);
            }
            c = __builtin_amdgcn_mfma_f32_16x16x32_bf16(aC, bC, c, 0, 0, 0);
            if (kt < 15) { aC = aN; bC = bN; }
        }
        #pragma unroll
        for (int r = 0; r < 4; ++r)
            inter[(size_t)(bt0 + quad * 4 + r) * 48 + w * 16 + l16] = c[r];
    }
}

// ---------------------------------------------------------------- kernel 2
// Round-2 structure (8 chunks x 2 kt, depth-1 V staging) + PINNED B-prefetch:
// per kt we issue this-kt A ds_reads and next-kt B global loads, then
// sched_barrier(0) stops the compiler from sinking the loads below the MFMA
// cluster (it was doing so to stay at VGPR<=64, which made the prefetch
// distance ~0 and exposed ~200cy L2 latency per kt -> MfmaUtil 13%).
// This deliberately trades occupancy (VGPR>64 -> 2 blocks/CU) for pipelining.
// History: (512,6) clamp -> VGPR 40 + 400MB spill (275us). Deep 4-kt chunks
// -> 30MB spill (183us). Keep launch_bounds(512,4); watch WRITE_SIZE.
__global__ __launch_bounds__(512, 4) void main_fused(
    const float* __restrict__ video, const float* __restrict__ bvid,
    const __bf16* __restrict__ wvid_k, const __bf16* __restrict__ wv_b,
    const float* __restrict__ Wh, const float* __restrict__ inter_g,
    float* __restrict__ out) {

    __shared__ uint4 pool4[3136];        // 50176 B: V granules, later vact rows
    __shared__ float inter_s[MDIM];
    __shared__ float z_s[MDIM];
    __shared__ float alpha_s[MDIM];
    __shared__ float content8[256];

    char* pool = (char*)pool4;

    const int bt   = blockIdx.x;
    const int tid  = threadIdx.x;
    const int w    = tid >> 6;
    const int lane = tid & 63;
    const int l16  = lane & 15;
    const int quad = lane >> 4;

    const float* Vg = video + (size_t)bt * (48 * 512);
    const char*  bbase = (const char*)wvid_k;

    // ---- phase 0
    if (tid < MDIM) { inter_s[tid] = inter_g[bt * MDIM + tid]; z_s[tid] = 0.f; }
    if (tid < 256) content8[tid] = 0.f;

    // staging ids (tid < 384 == waves 0..5, wave-uniform predicate):
    // granule (s_a, kc = c*8 + kcl); 8 lanes share an s-row -> 256B coalesced
    const int  s_a    = tid >> 3;
    const int  kcl    = tid & 7;
    const bool stager = (tid < 384);

    // ---- prologue: stage chunk 0 (kc 0..7, all s)
    if (stager) {
        const float4* p4 = (const float4*)(Vg + s_a * 512 + kcl * 8);
        float4 x = p4[0], y = p4[1];
        bf16x8 g = {(__bf16)x.x, (__bf16)x.y, (__bf16)x.z, (__bf16)x.w,
                    (__bf16)y.x, (__bf16)y.y, (__bf16)y.z, (__bf16)y.w};
        *(bf16x8*)(pool + (kcl * 49 + s_a) * 16) = g;
    }

    // first B fragments (kt = 0) issued before the barrier
    const int bIdx0 = quad * 8192 + (w * 64 + l16) * 16;
    bf16x8 bC[4];
    #pragma unroll
    for (int j = 0; j < 4; ++j)
        bC[j] = *(const bf16x8*)(bbase + bIdx0 + j * 256);

    f32x4 acc[3][4];
    #pragma unroll
    for (int mt = 0; mt < 3; ++mt)
        #pragma unroll
        for (int j = 0; j < 4; ++j) {
            f32x4 z = {0.f, 0.f, 0.f, 0.f};
            acc[mt][j] = z;
        }

    __syncthreads();

    // ---- pipelined phase 1+2: 8 chunks x 2 kt, loads pinned ahead of MFMA
    #pragma unroll
    for (int c = 0; c < 8; ++c) {
        float4 sx, sy;
        if (c < 7 && stager) {
            const float4* p4 = (const float4*)(Vg + s_a * 512 + ((c + 1) * 8 + kcl) * 8);
            sx = p4[0]; sy = p4[1];
        }
        #pragma unroll
        for (int k = 0; k < 2; ++k) {
            const int kt = c * 2 + k;
            // this-kt A fragments (LDS) — issue first so lgkm latency overlaps
            bf16x8 a[3];
            #pragma unroll
            for (int mt = 0; mt < 3; ++mt)
                a[mt] = *(const bf16x8*)(pool + ((4 * kt + quad) * 49 + mt * 16 + l16) * 16);
            // next-kt B fragments (global, L2-hot) — issue before MFMA cluster
            bf16x8 bN[4];
            if (kt < 15) {
                #pragma unroll
                for (int j = 0; j < 4; ++j)
                    bN[j] = *(const bf16x8*)(bbase + bIdx0 + (kt + 1) * 32768 + j * 256);
            }
            // pin: loads above may NOT sink below this point
            __builtin_amdgcn_sched_barrier(0);
            #pragma unroll
            for (int mt = 0; mt < 3; ++mt)
                #pragma unroll
                for (int j = 0; j < 4; ++j)
                    acc[mt][j] = __builtin_amdgcn_mfma_f32_16x16x32_bf16(
                                     a[mt], bC[j], acc[mt][j], 0, 0, 0);
            if (kt < 15) {
                #pragma unroll
                for (int j = 0; j < 4; ++j) bC[j] = bN[j];
            }
        }
        if (c < 7 && stager) {
            bf16x8 g = {(__bf16)sx.x, (__bf16)sx.y, (__bf16)sx.z, (__bf16)sx.w,
                        (__bf16)sy.x, (__bf16)sy.y, (__bf16)sy.z, (__bf16)sy.w};
            *(bf16x8*)(pool + (((c + 1) * 8 + kcl) * 49 + s_a) * 16) = g;
        }
        __syncthreads();   // chunk c+1 visible; doubles as "reads done" at c=7
    }

    // epilogue: relu+bias -> vact rows of 1040 B. D: row(s)=quad*4+r, col(h)=l16
    #pragma unroll
    for (int j = 0; j < 4; ++j) {
        int h = w * 64 + j * 16 + l16;
        float bias = bvid[h];            // L2-hot scalar load
        #pragma unroll
        for (int mt = 0; mt < 3; ++mt) {
            #pragma unroll
            for (int r = 0; r < 4; ++r) {
                int s = mt * 16 + quad * 4 + r;
                *(__bf16*)(pool + s * 1040 + h * 2) =
                    (__bf16)fmaxf(acc[mt][j][r] + bias, 0.f);
            }
        }
    }
    __syncthreads();

    // ---- phase 3: content = vact @ Wv^T + inter; z[s] += tanh(.)*Wh[m]
    {
        int ti = w / 3, tj = w - ti * 3;    // tiles 0..7; tile 8 split below
        const __bf16* bp = wv_b + (size_t)(tj * 16 + l16) * 512 + quad * 8;
        const char*   ap = pool + (ti * 16 + l16) * 1040 + quad * 16;
        // two interleaved accumulators halve the dependent-MFMA chain
        f32x4 c3e = {0.f, 0.f, 0.f, 0.f};
        f32x4 c3o = {0.f, 0.f, 0.f, 0.f};
        #pragma unroll
        for (int kt = 0; kt < 16; kt += 2) {
            bf16x8 a0 = *(const bf16x8*)(ap + kt * 64);
            bf16x8 b0 = *(const bf16x8*)(bp + kt * 32);
            c3e = __builtin_amdgcn_mfma_f32_16x16x32_bf16(a0, b0, c3e, 0, 0, 0);
            bf16x8 a1 = *(const bf16x8*)(ap + (kt + 1) * 64);
            bf16x8 b1 = *(const bf16x8*)(bp + (kt + 1) * 32);
            c3o = __builtin_amdgcn_mfma_f32_16x16x32_bf16(a1, b1, c3o, 0, 0, 0);
        }
        f32x4 c3 = c3e + c3o;
        float wh = Wh[tj * 16 + l16];
        #pragma unroll
        for (int r = 0; r < 4; ++r) {
            int s = ti * 16 + quad * 4 + r;
            float contrib = tanhf(c3[r] + inter_s[s]) * wh;
            contrib += __shfl_xor(contrib, 1);
            contrib += __shfl_xor(contrib, 2);
            contrib += __shfl_xor(contrib, 4);
            contrib += __shfl_xor(contrib, 8);
            if (l16 == 0) atomicAdd(&z_s[s], contrib);
        }
        // tile 8 (ti=2,tj=2): wave w does kt = 2w, 2w+1
        f32x4 p8 = {0.f, 0.f, 0.f, 0.f};
        #pragma unroll
        for (int q = 0; q < 2; ++q) {
            int kt = 2 * w + q;
            bf16x8 a8 = *(const bf16x8*)(pool + (32 + l16) * 1040 + kt * 64 + quad * 16);
            bf16x8 b8 = *(const bf16x8*)(wv_b + (size_t)(32 + l16) * 512 + kt * 32 + quad * 8);
            p8 = __builtin_amdgcn_mfma_f32_16x16x32_bf16(a8, b8, p8, 0, 0, 0);
        }
        #pragma unroll
        for (int r = 0; r < 4; ++r)
            atomicAdd(&content8[(quad * 4 + r) * 16 + l16], p8[r]);
    }
    __syncthreads();

    if (w == 0) {
        float wh = Wh[32 + l16];
        #pragma unroll
        for (int r = 0; r < 4; ++r) {
            int s = 32 + quad * 4 + r;
            float contrib = tanhf(content8[(quad * 4 + r) * 16 + l16] + inter_s[s]) * wh;
            contrib += __shfl_xor(contrib, 1);
            contrib += __shfl_xor(contrib, 2);
            contrib += __shfl_xor(contrib, 4);
            contrib += __shfl_xor(contrib, 8);
            if (l16 == 0) atomicAdd(&z_s[s], contrib);
        }
    }
    __syncthreads();

    // ---- phase 4: softmax over z[48] (wave 0)
    if (w == 0) {
        float x = (lane < MDIM) ? z_s[lane] : -INFINITY;
        float mx = x;
        #pragma unroll
        for (int off = 32; off >= 1; off >>= 1) mx = fmaxf(mx, __shfl_xor(mx, off));
        float e = (lane < MDIM) ? expf(x - mx) : 0.f;
        float sm = e;
        #pragma unroll
        for (int off = 32; off >= 1; off >>= 1) sm += __shfl_xor(sm, off);
        if (lane < MDIM) alpha_s[lane] = e / sm;
    }
    __syncthreads();

    // ---- phase 5: c[h] = sum_s alpha[s] * V[s][h] (fp32 global, L2/L3-hot)
    float acc5 = 0.f;
    #pragma unroll
    for (int s = 0; s < MDIM; ++s)
        acc5 += alpha_s[s] * Vg[s * 512 + tid];
    out[(size_t)bt * 512 + tid] = acc5;
}

// ---------------------------------------------------------------- launch
extern "C" void kernel_launch(void* const* d_in, const int* in_sizes, int n_in,
                              void* d_out, int out_size, void* d_ws, size_t ws_size,
                              hipStream_t stream) {
    const float* audio   = (const float*)d_in[0];
    const float* video   = (const float*)d_in[1];
    const float* W_audio = (const float*)d_in[2];
    const float* b_audio = (const float*)d_in[3];
    const float* W_video = (const float*)d_in[4];
    const float* b_video = (const float*)d_in[5];
    const float* W_v     = (const float*)d_in[6];
    const float* W_g     = (const float*)d_in[7];
    const float* W_h     = (const float*)d_in[8];
    float* out = (float*)d_out;

    char* ws = (char*)d_ws;
    __bf16* wvid_k = (__bf16*)(ws + WS_WVID);
    __bf16* wv_b   = (__bf16*)(ws + WS_WV);
    __bf16* wg_b   = (__bf16*)(ws + WS_WG);
    float*  inter  = (float*)(ws + WS_INTER);

    convert_weights<<<304, 256, 0, stream>>>(W_video, W_v, W_g, wvid_k, wv_b, wg_b);
    audio_batch<<<BT / 16, 512, 0, stream>>>(audio, W_audio, b_audio, wg_b, inter);
    main_fused<<<BT, 512, 0, stream>>>(video, b_video, wvid_k, wv_b, W_h, inter, out);
}